// Round 4
// baseline (248.905 us; speedup 1.0000x reference)
//
#include <hip/hip_runtime.h>
#include <hip/hip_bf16.h>

#define NB 8192   // batch
#define ND 1024   // feature dim

typedef __bf16 bf16x8 __attribute__((ext_vector_type(8)));
typedef float  f32x4  __attribute__((ext_vector_type(4)));

// async global -> LDS, 16B per lane. LDS dest = wave-uniform base + lane*16.
__device__ inline void gload_lds16(const void* g, void* l) {
    __builtin_amdgcn_global_load_lds(
        (const __attribute__((address_space(1))) unsigned int*)g,
        (__attribute__((address_space(3))) unsigned int*)l,
        16, 0, 0);
}

__device__ inline unsigned short f2bf(float x) {
    unsigned int u = __float_as_uint(x);
    return (unsigned short)((u + 0x7fffu + ((u >> 16) & 1u)) >> 16);
}

#define BARRIER() asm volatile("s_barrier" ::: "memory")
#define VMCNT0()  asm volatile("s_waitcnt vmcnt(0)" ::: "memory")
#define LGKM0()   do { asm volatile("s_waitcnt lgkmcnt(0)" ::: "memory"); \
                       __builtin_amdgcn_sched_barrier(0); } while (0)

// ---------------------------------------------------------------------------
// Kernel 1: per-row L2 norms of A and B + bf16 conversion into workspace.
// ---------------------------------------------------------------------------
__global__ __launch_bounds__(256) void prep_kernel(
    const float* __restrict__ A, const float* __restrict__ Bm,
    unsigned short* __restrict__ wa, unsigned short* __restrict__ wb,
    float* __restrict__ na, float* __restrict__ nb)
{
    int b = blockIdx.x;
    int wid = threadIdx.x >> 6, lane = threadIdx.x & 63;
    const float* src; unsigned short* dst; float* nrm; int row;
    if (b < 2048) { src = A;  dst = wa; nrm = na; row = b * 4 + wid; }
    else          { src = Bm; dst = wb; nrm = nb; row = (b - 2048) * 4 + wid; }

    const float*    rp = src + (size_t)row * ND;
    unsigned short* wp = dst + (size_t)row * ND;

    float ss = 0.f;
#pragma unroll
    for (int t = 0; t < 4; ++t) {
        int c = lane * 4 + t * 256;
        float4 v = *reinterpret_cast<const float4*>(rp + c);
        ss += v.x * v.x + v.y * v.y + v.z * v.z + v.w * v.w;
        ushort4 u;
        u.x = f2bf(v.x); u.y = f2bf(v.y); u.z = f2bf(v.z); u.w = f2bf(v.w);
        *reinterpret_cast<ushort4*>(wp + c) = u;
    }
#pragma unroll
    for (int off = 32; off; off >>= 1) ss += __shfl_xor(ss, off);
    if (lane == 0) nrm[row] = sqrtf(ss);
}

// ---------------------------------------------------------------------------
// Kernel 2: label histogram (integer LDS atomics -> deterministic).
// ---------------------------------------------------------------------------
__global__ __launch_bounds__(256) void hist_kernel(
    const int* __restrict__ labels, int* __restrict__ hist)
{
    __shared__ int h[128];
    int tid = threadIdx.x;
    if (tid < 128) h[tid] = 0;
    __syncthreads();
    for (int i = tid; i < NB; i += 256) atomicAdd(&h[labels[i]], 1);
    __syncthreads();
    if (tid < 128) hist[tid] = h[tid];
}

// ---------------------------------------------------------------------------
// Kernel 3: 256x256-tile bf16 GEMM, BK=64, 8-phase template (T2+T3+T4+T5).
// 2 LDS buffers (64 KiB each). Tile t+1 staged into buf^1 during tile t's
// phases 1-2; one vmcnt(0) gate at phase 4 (loads issued 2-3 phases earlier
// -> ~zero wait). Per phase: {ds_read frags; stage; s_barrier; lgkmcnt(0)+
// sched_barrier; setprio(1); 16 MFMA; setprio(0); s_barrier}.
// LDS rows are 64 cols (128 B): granule swizzle g ^= (row&7) on both the
// pre-swizzled global source and the ds_read address.
// Epilogue: scale to cos, write C, reduce per-row loss partials (fused).
// ---------------------------------------------------------------------------
__global__ __launch_bounds__(512, 2) void gemm_cos(
    const unsigned short* __restrict__ wa, const unsigned short* __restrict__ wb,
    const float* __restrict__ na, const float* __restrict__ nb,
    const int* __restrict__ labels,
    float* __restrict__ C, float* __restrict__ pe, float* __restrict__ pm)
{
    // [buf 2][ A 256x64 | B 256x64 ] bf16 = 2 x 32768 shorts = 128 KiB
    __shared__ unsigned short lds[65536];

    const int bid = blockIdx.x;                 // 1024 blocks
    const int tm  = (bid & 7) * 4 + ((bid >> 3) & 3);
    const int tn  = bid >> 5;

    const int tid  = threadIdx.x;
    const int lane = tid & 63;
    const int wid  = tid >> 6;
    const int wr   = wid >> 2, wc = wid & 3;
    const int l15  = lane & 15, lg = lane >> 4;   // lg in 0..3

    const int m0 = tm * 256, n0 = tn * 256;

    // ---- staging addressing: one gload call = 64 rows x 64 cols (4096 sh).
    // thread tid -> row tid>>3, LDS granule tid&7 ; global granule is
    // pre-swizzled: (tid&7) ^ (row&7)  (so LDS[r][g] holds global g^(r&7)).
    const int srow6 = tid >> 3;                       // 0..63
    const int sgr   = (tid & 7) ^ (srow6 & 7);
    const unsigned short* pA = wa + (size_t)(m0 + srow6) * ND + sgr * 8;
    const unsigned short* pB = wb + (size_t)(n0 + srow6) * ND + sgr * 8;
    const int stW = wid * 512;       // wave-uniform dest base within a chunk
    const int ND64 = 64 * ND;

    // ---- fragment read addressing (shorts). row*64 + swzg*8, where
    // swzg = (ks*4 + lg) ^ (row&7); row&7 == l15&7 here. ks flips addr bit 5.
    const int swz0  = ((((l15 >> 2) & 1) << 2) | (lg ^ (l15 & 3))) * 8;
    const int baseA = (wr * 128 + l15) * 64 + swz0;
    const int baseB = 16384 + (wc * 64 + l15) * 64 + swz0;

    f32x4 acc[8][4];
#pragma unroll
    for (int i = 0; i < 8; ++i)
#pragma unroll
        for (int j = 0; j < 4; ++j) acc[i][j] = (f32x4){0.f, 0.f, 0.f, 0.f};

    bf16x8 bq[4];

#define STG4(P, DST) do { \
    gload_lds16((P),            &lds[(DST) + 0 * 4096 + stW]); \
    gload_lds16((P) +     ND64, &lds[(DST) + 1 * 4096 + stW]); \
    gload_lds16((P) + 2 * ND64, &lds[(DST) + 2 * 4096 + stW]); \
    gload_lds16((P) + 3 * ND64, &lds[(DST) + 3 * 4096 + stW]); } while (0)

#define PH(BUFB, KS, MH, RB, GATE, ...) { \
    if (RB) { _Pragma("unroll") \
        for (int n_ = 0; n_ < 4; ++n_) \
            bq[n_] = *reinterpret_cast<const bf16x8*>( \
                &lds[(BUFB) + ((baseB + n_ * 1024) ^ ((KS) * 32))]); } \
    bf16x8 af[4]; \
    _Pragma("unroll") \
    for (int m_ = 0; m_ < 4; ++m_) \
        af[m_] = *reinterpret_cast<const bf16x8*>( \
            &lds[(BUFB) + ((baseA + ((MH) * 4 + m_) * 1024) ^ ((KS) * 32))]); \
    __VA_ARGS__; \
    BARRIER(); \
    LGKM0(); \
    __builtin_amdgcn_s_setprio(1); \
    _Pragma("unroll") \
    for (int m_ = 0; m_ < 4; ++m_) \
        _Pragma("unroll") \
        for (int n_ = 0; n_ < 4; ++n_) \
            acc[(MH) * 4 + m_][n_] = __builtin_amdgcn_mfma_f32_16x16x32_bf16( \
                af[m_], bq[n_], acc[(MH) * 4 + m_][n_], 0, 0, 0); \
    __builtin_amdgcn_s_setprio(0); \
    if (GATE) VMCNT0(); \
    BARRIER(); }

    // Prologue: stage tile 0 into buf0.
    STG4(pA, 0); STG4(pB, 16384);
    VMCNT0();
    BARRIER();

    for (int j = 0; j < 8; ++j) {
        const unsigned short* s1 = pA + (2 * j + 1) * 64;
        const unsigned short* t1 = pB + (2 * j + 1) * 64;
        // tile 2j from buf0; stage tile 2j+1 -> buf1 at phases 1-2
        PH(0, 0, 0, 1, 0, STG4(s1, 32768))
        PH(0, 0, 1, 0, 0, STG4(t1, 32768 + 16384))
        PH(0, 1, 0, 1, 0, (void)0)
        PH(0, 1, 1, 0, 1, (void)0)
        // tile 2j+1 from buf1; stage tile 2j+2 -> buf0 (skip on last iter)
        if (j < 7) {
            const unsigned short* s2 = pA + (2 * j + 2) * 64;
            const unsigned short* t2 = pB + (2 * j + 2) * 64;
            PH(32768, 0, 0, 1, 0, STG4(s2, 0))
            PH(32768, 0, 1, 0, 0, STG4(t2, 16384))
            PH(32768, 1, 0, 1, 0, (void)0)
            PH(32768, 1, 1, 0, 1, (void)0)
        } else {
            PH(32768, 0, 0, 1, 0, (void)0)
            PH(32768, 0, 1, 0, 0, (void)0)
            PH(32768, 1, 0, 1, 0, (void)0)
            PH(32768, 1, 1, 0, 1, (void)0)
        }
    }

#undef PH
#undef STG4

    // ---------------- epilogue: cos write + fused loss partials ------------
    __syncthreads();                 // full drain; LDS buffers now reusable
    float* pl = reinterpret_cast<float*>(lds);   // [256 rows][4 wc][2] floats

    float nbv[4]; int labc[4];
#pragma unroll
    for (int n = 0; n < 4; ++n) {
        int c = n0 + wc * 64 + n * 16 + l15;
        nbv[n] = nb[c]; labc[n] = labels[c];
    }

#pragma unroll
    for (int m = 0; m < 8; ++m) {
#pragma unroll
        for (int jj = 0; jj < 4; ++jj) {
            int rl = wr * 128 + m * 16 + lg * 4 + jj;   // 0..255
            int r  = m0 + rl;
            float nav = na[r]; int labr = labels[r];
            float es = 0.f, ms = 0.f;
#pragma unroll
            for (int n = 0; n < 4; ++n) {
                int c = n0 + wc * 64 + n * 16 + l15;
                float v = acc[m][n][jj] / fmaxf(nav * nbv[n], 1e-8f);
                C[(size_t)r * NB + c] = v;
                es += __expf(v);
                ms += (labc[n] == labr) ? v : 0.f;
            }
#pragma unroll
            for (int off = 1; off < 16; off <<= 1) {
                es += __shfl_xor(es, off);
                ms += __shfl_xor(ms, off);
            }
            if (l15 == 0) {
                int o = (rl * 4 + wc) * 2;
                pl[o] = es; pl[o + 1] = ms;
            }
        }
    }
    __syncthreads();
    if (tid < 256) {
        float es = 0.f, ms = 0.f;
#pragma unroll
        for (int w = 0; w < 4; ++w) {
            es += pl[(tid * 4 + w) * 2];
            ms += pl[(tid * 4 + w) * 2 + 1];
        }
        int grow = m0 + tid;
        pe[tn * NB + grow] = es;
        pm[tn * NB + grow] = ms;
    }
}

// ---------------------------------------------------------------------------
// Kernel 4: reduce column-tile partials -> per-row loss.
// ---------------------------------------------------------------------------
__global__ __launch_bounds__(256) void loss_final(
    const float* __restrict__ pe, const float* __restrict__ pm,
    const int* __restrict__ labels, const int* __restrict__ hist,
    float* __restrict__ per_row)
{
    int row = blockIdx.x * 256 + threadIdx.x;
    float es = 0.f, ms = 0.f;
#pragma unroll
    for (int t = 0; t < 32; ++t) {
        es += pe[t * NB + row];
        ms += pm[t * NB + row];
    }
    per_row[row] = logf(es) - ms / (float)hist[labels[row]];
}

// ---------------------------------------------------------------------------
// Kernel 5: deterministic mean of per_row -> out[0]
// ---------------------------------------------------------------------------
__global__ __launch_bounds__(256) void finalize(
    const float* __restrict__ per_row, float* __restrict__ out)
{
    __shared__ float sm[256];
    float s = 0.f;
    for (int i = threadIdx.x; i < NB; i += 256) s += per_row[i];
    sm[threadIdx.x] = s;
    __syncthreads();
    for (int k = 128; k; k >>= 1) {
        if (threadIdx.x < k) sm[threadIdx.x] += sm[threadIdx.x + k];
        __syncthreads();
    }
    if (threadIdx.x == 0) out[0] = sm[0] * (1.0f / (float)NB);
}

extern "C" void kernel_launch(void* const* d_in, const int* in_sizes, int n_in,
                              void* d_out, int out_size, void* d_ws, size_t ws_size,
                              hipStream_t stream) {
    const int*   labels = (const int*)d_in[0];
    const float* A      = (const float*)d_in[1];
    const float* Bm     = (const float*)d_in[2];
    float* out = (float*)d_out;

    // workspace layout (~36.2 MB)
    char* ws = (char*)d_ws;
    unsigned short* wa = (unsigned short*)(ws);                     // 16 MB
    unsigned short* wb = (unsigned short*)(ws + 16777216);          // 16 MB
    float* na      = (float*)(ws + 33554432);                       // 32 KB
    float* nb      = (float*)(ws + 33554432 + 32768);               // 32 KB
    float* per_row = (float*)(ws + 33554432 + 65536);               // 32 KB
    int*   hist    = (int*)  (ws + 33554432 + 98304);               // 512 B
    float* pe      = (float*)(ws + 33554432 + 131072);              // 1 MB
    float* pm      = (float*)(ws + 33554432 + 131072 + 1048576);    // 1 MB

    float* cosm = out + 1;   // out[0]=loss, out[1..] = cos_score row-major

    prep_kernel<<<4096, 256, 0, stream>>>(A, Bm, wa, wb, na, nb);
    hist_kernel<<<1,    256, 0, stream>>>(labels, hist);
    gemm_cos   <<<1024, 512, 0, stream>>>(wa, wb, na, nb, labels, cosm, pe, pm);
    loss_final <<<32,   256, 0, stream>>>(pe, pm, labels, hist, per_row);
    finalize   <<<1,    256, 0, stream>>>(per_row, out);
}